// Round 4
// baseline (97.074 us; speedup 1.0000x reference)
//
#include <hip/hip_runtime.h>
#include <math.h>

#define BB 2
#define SS 4096
#define HH 16
#define DD 128
#define CK 64
#define NTC 64
#define HD 2048          // H*D row stride (elements)
#define SQ 136           // LDS row stride (shorts), rows of 128 (q, k)
#define ST 72            // LDS row stride (shorts), rows of 64 (kT, vT)

typedef __attribute__((ext_vector_type(8))) short bh8;     // 8 bf16
typedef __attribute__((ext_vector_type(16))) float fx16;   // 32x32 accumulator

#define MFMA32(a, b, c) __builtin_amdgcn_mfma_f32_32x32x16_bf16(a, b, c, 0, 0, 0)

__device__ inline unsigned short f2bf(float f) {
    unsigned int u = __float_as_uint(f);
    return (unsigned short)((u + 0x7FFFu + ((u >> 16) & 1u)) >> 16);  // RNE
}
__device__ inline unsigned int pk2(float a, float b) {
    return (unsigned int)f2bf(a) | ((unsigned int)f2bf(b) << 16);
}

// exchange: x' = {x.lo, y.lo(from partner)}, y' = {x.hi(from partner), y.hi}
#define SWAP32(x, y) asm("v_permlane32_swap_b32 %0, %1" : "+v"(x), "+v"(y))

// Build an MFMA A/B fragment (8 consecutive k per hi-half) from 8 C/D-layout
// f32 regs (C/D rows (rg&3)+8*(rg>>2)+4*hi). One swap fixes the hi mismatch.
#define MKFRAG(dst, cc, O) { \
    unsigned a0_ = pk2(cc[(O)+0], cc[(O)+1]), a1_ = pk2(cc[(O)+2], cc[(O)+3]); \
    unsigned a2_ = pk2(cc[(O)+4], cc[(O)+5]), a3_ = pk2(cc[(O)+6], cc[(O)+7]); \
    SWAP32(a0_, a2_); SWAP32(a1_, a3_); \
    union { unsigned u[4]; bh8 v; } r_; \
    r_.u[0] = a0_; r_.u[1] = a1_; r_.u[2] = a2_; r_.u[3] = a3_; \
    dst = r_.v; }

// ---------------- Phase 1: per-group K^T V sums (dbuf, reg-h, tile-major G) ----------
__global__ __launch_bounds__(512, 4) void ksum_kernel(const float* __restrict__ k,
                                                      const float* __restrict__ v,
                                                      float* __restrict__ G,
                                                      int CPG, int NG) {
    int g = blockIdx.x, h = blockIdx.y, b = blockIdx.z;
    int t = threadIdx.x, l = t & 63, w = t >> 6, hi = l >> 5, lm = l & 31;
    int dbp = 2 * (w >> 2), eb = w & 3;   // wave owns h tiles (dbp,eb),(dbp+1,eb)
    __shared__ short lkT[2][128 * ST];
    __shared__ short lvT[2][128 * ST];
    fx16 h0 = {}, h1 = {};
    long hbase = ((long)b * SS) * HD + (long)h * DD;
    float kt[16], vt[16];

#define KLOAD(cc) { long base_ = hbase + (long)(g * CPG + (cc)) * CK * HD; \
    _Pragma("unroll") for (int i = 0; i < 8; ++i) { int it = t + 512 * i; \
        int e = (it & 31) + 32 * (it >> 10); int c2 = (it >> 5) & 31; \
        long ga = base_ + (long)(2 * c2) * HD + e; \
        kt[2*i] = k[ga]; kt[2*i+1] = k[ga + HD]; \
        vt[2*i] = v[ga]; vt[2*i+1] = v[ga + HD]; } }

#define KSTAGE(pn) { \
    _Pragma("unroll") for (int i = 0; i < 8; ++i) { int it = t + 512 * i; \
        int e = (it & 31) + 32 * (it >> 10); int c2 = (it >> 5) & 31; \
        *(unsigned*)&lkT[pn][e * ST + 2 * c2] = pk2(kt[2*i], kt[2*i+1]); \
        *(unsigned*)&lvT[pn][e * ST + 2 * c2] = pk2(vt[2*i], vt[2*i+1]); } }

    KLOAD(0); KSTAGE(0); if (CPG > 1) KLOAD(1);
    __syncthreads();
    int p = 0;
    for (int c = 0; c < CPG; ++c) {
        if (c + 1 < CPG) KSTAGE(p ^ 1);
        if (c + 2 < CPG) KLOAD(c + 2);
        bh8 Bv0 = *(const bh8*)&lvT[p][(32*eb+lm)*ST +  0 + 8*hi];
        bh8 Bv1 = *(const bh8*)&lvT[p][(32*eb+lm)*ST + 16 + 8*hi];
        bh8 Bv2 = *(const bh8*)&lvT[p][(32*eb+lm)*ST + 32 + 8*hi];
        bh8 Bv3 = *(const bh8*)&lvT[p][(32*eb+lm)*ST + 48 + 8*hi];
#define KM4(hx, db) { \
        bh8 A0_ = *(const bh8*)&lkT[p][(32*(db)+lm)*ST +  0 + 8*hi]; hx = MFMA32(A0_, Bv0, hx); \
        bh8 A1_ = *(const bh8*)&lkT[p][(32*(db)+lm)*ST + 16 + 8*hi]; hx = MFMA32(A1_, Bv1, hx); \
        bh8 A2_ = *(const bh8*)&lkT[p][(32*(db)+lm)*ST + 32 + 8*hi]; hx = MFMA32(A2_, Bv2, hx); \
        bh8 A3_ = *(const bh8*)&lkT[p][(32*(db)+lm)*ST + 48 + 8*hi]; hx = MFMA32(A3_, Bv3, hx); }
        KM4(h0, dbp) KM4(h1, dbp + 1)
        __syncthreads();
        p ^= 1;
    }
    // tile-major fragment-ordered G: tile (db,eb) at (db*4+eb)*1024 + lane*16
    float* Gp = G + ((long)(b * HH + h) * NG + g) * (DD * DD);
    long t0 = (long)((dbp) * 4 + eb) * 1024 + l * 16;
    long t1 = (long)((dbp + 1) * 4 + eb) * 1024 + l * 16;
#pragma unroll
    for (int q4 = 0; q4 < 4; ++q4) {
        *(float4*)&Gp[t0 + 4*q4] = make_float4(h0[4*q4], h0[4*q4+1], h0[4*q4+2], h0[4*q4+3]);
        *(float4*)&Gp[t1 + 4*q4] = make_float4(h1[4*q4], h1[4*q4+1], h1[4*q4+2], h1[4*q4+3]);
    }
}

// ---------------- Phase 2: exclusive prefix over groups (in-place, frag-ordered) -----
__global__ __launch_bounds__(256) void prefix_kernel(float* __restrict__ G,
                                                     float* __restrict__ hf,
                                                     int NG) {
    int tid = blockIdx.x * 256 + threadIdx.x;
    int bh = tid >> 11;
    int fl = (tid & 2047) * 8;
    float* Gb = G + (long)bh * NG * (DD * DD) + fl;
    float4 a0 = make_float4(0.f, 0.f, 0.f, 0.f), a1 = a0;
    for (int g = 0; g < NG; ++g) {
        float* p = Gb + (long)g * (DD * DD);
        float4 v0 = *(float4*)p;
        float4 v1 = *(float4*)(p + 4);
        *(float4*)p       = a0;
        *(float4*)(p + 4) = a1;
        a0.x += v0.x; a0.y += v0.y; a0.z += v0.z; a0.w += v0.w;
        a1.x += v1.x; a1.y += v1.y; a1.z += v1.z; a1.w += v1.w;
    }
    // scatter running total into semantic final_state hf[d][e]
    float acc[8] = {a0.x, a0.y, a0.z, a0.w, a1.x, a1.y, a1.z, a1.w};
    float* hb = hf + (long)bh * (DD * DD);
    int tile = fl >> 10, li = (fl >> 4) & 63;
#pragma unroll
    for (int j = 0; j < 8; ++j) {
        int rg = (fl & 15) + j;
        int d = 32 * (tile >> 2) + (rg & 3) + 8 * (rg >> 2) + 4 * (li >> 5);
        int e = 32 * (tile & 3) + (li & 31);
        hb[d * DD + e] = acc[j];
    }
}

// ---------------- Phase 3: scan (dbuf, reg S^T, reg h, 1 barrier/chunk) --------------
__global__ __launch_bounds__(512, 2) void scan_kernel(const float* __restrict__ q,
                                                      const float* __restrict__ kk,
                                                      const float* __restrict__ vv,
                                                      const float* __restrict__ G,
                                                      float* __restrict__ o,
                                                      int CPG, int NG, float scale) {
    int g = blockIdx.x, h = blockIdx.y, b = blockIdx.z;
    int t = threadIdx.x, l = t & 63, w = t >> 6, hi = l >> 5, lm = l & 31;
    int rb = w >> 2, eb = w & 3;   // o-tile (rb,eb); h e-slice eb (dup across rb)
    __shared__ short lq [2][64 * SQ];
    __shared__ short lk [2][64 * SQ];
    __shared__ short lkT[2][128 * ST];
    __shared__ short lvT[2][128 * ST];

    // h state: 4 tiles (db=0..3) of e-slice eb, C/D layout (col=e, rows=d-frag)
    fx16 h0 = {}, h1 = {}, h2 = {}, h3 = {};
    {
        const float* Gp = G + ((long)(b * HH + h) * NG + g) * (DD * DD);
#define GINIT(hx, db) { const float* p_ = Gp + (long)((db) * 4 + eb) * 1024 + l * 16; \
        _Pragma("unroll") for (int q4 = 0; q4 < 4; ++q4) { \
            float4 x_ = *(const float4*)&p_[4*q4]; \
            hx[4*q4] = x_.x; hx[4*q4+1] = x_.y; hx[4*q4+2] = x_.z; hx[4*q4+3] = x_.w; } }
        GINIT(h0, 0) GINIT(h1, 1) GINIT(h2, 2) GINIT(h3, 3)
    }

    long hbase = ((long)b * SS) * HD + (long)h * DD;
    float4 qv[4], kv[4];
    float kt[16], vt[16];
    int r8 = t >> 3, c8 = t & 7;

#define SLOAD(cc) { long base_ = hbase + (long)(g * CPG + (cc)) * CK * HD; \
    _Pragma("unroll") for (int j = 0; j < 4; ++j) { \
        long ga = base_ + (long)r8 * HD + 4 * c8 + 32 * j; \
        qv[j] = *(const float4*)&q[ga]; kv[j] = *(const float4*)&kk[ga]; } \
    _Pragma("unroll") for (int i = 0; i < 8; ++i) { int it = t + 512 * i; \
        int e = (it & 31) + 32 * (it >> 10); int c2 = (it >> 5) & 31; \
        long ga = base_ + (long)(2 * c2) * HD + e; \
        kt[2*i] = kk[ga]; kt[2*i+1] = kk[ga + HD]; \
        vt[2*i] = vv[ga]; vt[2*i+1] = vv[ga + HD]; } }

#define SSTAGE(pn) { \
    _Pragma("unroll") for (int j = 0; j < 4; ++j) { \
        uint2 uq_; uq_.x = pk2(qv[j].x * scale, qv[j].y * scale); \
        uq_.y = pk2(qv[j].z * scale, qv[j].w * scale); \
        *(uint2*)&lq[pn][r8 * SQ + 4 * c8 + 32 * j] = uq_; \
        uint2 uk_; uk_.x = pk2(kv[j].x, kv[j].y); uk_.y = pk2(kv[j].z, kv[j].w); \
        *(uint2*)&lk[pn][r8 * SQ + 4 * c8 + 32 * j] = uk_; } \
    _Pragma("unroll") for (int i = 0; i < 8; ++i) { int it = t + 512 * i; \
        int e = (it & 31) + 32 * (it >> 10); int c2 = (it >> 5) & 31; \
        *(unsigned*)&lkT[pn][e * ST + 2 * c2] = pk2(kt[2*i], kt[2*i+1]); \
        *(unsigned*)&lvT[pn][e * ST + 2 * c2] = pk2(vt[2*i], vt[2*i+1]); } }

    SLOAD(0); SSTAGE(0); if (CPG > 1) SLOAD(1);
    __syncthreads();
    int p = 0;

    for (int c = 0; c < CPG; ++c) {
        long base = hbase + (long)(g * CPG + c) * CK * HD;
        if (c + 1 < CPG) SSTAGE(p ^ 1);

        // ---- m1: S^T tiles (cb, rb) in regs: A=k rows(cb), B=q rows(rb) ----
        fx16 sa0 = {}, sa1 = {};
#pragma unroll
        for (int ks = 0; ks < 8; ++ks) {
            bh8 Bq = *(const bh8*)&lq[p][(32*rb+lm)*SQ + 16*ks + 8*hi];
            bh8 A0 = *(const bh8*)&lk[p][lm*SQ + 16*ks + 8*hi];
            sa0 = MFMA32(A0, Bq, sa0);
            if (rb) {
                bh8 A1 = *(const bh8*)&lk[p][(32+lm)*SQ + 16*ks + 8*hi];
                sa1 = MFMA32(A1, Bq, sa1);
            }
        }
        // ---- mask + convert S^T to m2 A-frags (in-register) ----
        bh8 fS0, fS1, fS2, fS3;
        {
            float ms[16];
            int rr = 32 * rb + lm;
            if (rb == 0) {   // single diagonal tile cb=0
#pragma unroll
                for (int rg = 0; rg < 16; ++rg) {
                    int cc_ = (rg & 3) + 8 * (rg >> 2) + 4 * hi;
                    ms[rg] = (cc_ <= rr) ? sa0[rg] : 0.f;
                }
                MKFRAG(fS0, ms, 0) MKFRAG(fS1, ms, 8)
                fS2 = fS0; fS3 = fS1;  // unused
            } else {         // cb=0 full, cb=1 diagonal
                MKFRAG(fS0, sa0, 0) MKFRAG(fS1, sa0, 8)
#pragma unroll
                for (int rg = 0; rg < 16; ++rg) {
                    int cc_ = 32 + (rg & 3) + 8 * (rg >> 2) + 4 * hi;
                    ms[rg] = (cc_ <= rr) ? sa1[rg] : 0.f;
                }
                MKFRAG(fS2, ms, 0) MKFRAG(fS3, ms, 8)
            }
        }
        if (c + 2 < CPG) SLOAD(c + 2);   // prefetch under m2..m4

        // shared B-operands from vT (e-slice eb), used by m2 and m4
        bh8 Bv0 = *(const bh8*)&lvT[p][(32*eb+lm)*ST +  0 + 8*hi];
        bh8 Bv1 = *(const bh8*)&lvT[p][(32*eb+lm)*ST + 16 + 8*hi];
        bh8 Bv2 = *(const bh8*)&lvT[p][(32*eb+lm)*ST + 32 + 8*hi];
        bh8 Bv3 = *(const bh8*)&lvT[p][(32*eb+lm)*ST + 48 + 8*hi];

        // ---- m2: o = S @ v ----
        fx16 oa = {};
        oa = MFMA32(fS0, Bv0, oa);
        oa = MFMA32(fS1, Bv1, oa);
        if (rb) {
            oa = MFMA32(fS2, Bv2, oa);
            oa = MFMA32(fS3, Bv3, oa);
        }
        // ---- m3: o += qs @ h (B-frags built from reg h, pre-update) ----
#define M3STEP(hx, db) { \
        bh8 Aq0 = *(const bh8*)&lq[p][(32*rb+lm)*SQ + 16*(2*(db)) + 8*hi]; \
        bh8 Bh0; MKFRAG(Bh0, hx, 0); oa = MFMA32(Aq0, Bh0, oa); \
        bh8 Aq1 = *(const bh8*)&lq[p][(32*rb+lm)*SQ + 16*(2*(db)+1) + 8*hi]; \
        bh8 Bh1; MKFRAG(Bh1, hx, 8); oa = MFMA32(Aq1, Bh1, oa); }
        M3STEP(h0, 0) M3STEP(h1, 1) M3STEP(h2, 2) M3STEP(h3, 3)

        // ---- m4: h += k^T v (A from lkT d-rows, B shared Bv) ----
#define M4STEP(hx, db) { \
        bh8 A0_ = *(const bh8*)&lkT[p][(32*(db)+lm)*ST +  0 + 8*hi]; hx = MFMA32(A0_, Bv0, hx); \
        bh8 A1_ = *(const bh8*)&lkT[p][(32*(db)+lm)*ST + 16 + 8*hi]; hx = MFMA32(A1_, Bv1, hx); \
        bh8 A2_ = *(const bh8*)&lkT[p][(32*(db)+lm)*ST + 32 + 8*hi]; hx = MFMA32(A2_, Bv2, hx); \
        bh8 A3_ = *(const bh8*)&lkT[p][(32*(db)+lm)*ST + 48 + 8*hi]; hx = MFMA32(A3_, Bv3, hx); }
        M4STEP(h0, 0) M4STEP(h1, 1) M4STEP(h2, 2) M4STEP(h3, 3)

        // ---- o write ----
        {
            float* op = o + base;
            int e = 32 * eb + lm;
#pragma unroll
            for (int rg = 0; rg < 16; ++rg) {
                int r = 32 * rb + (rg & 3) + 8 * (rg >> 2) + 4 * hi;
                op[(long)r * HD + e] = oa[rg];
            }
        }
        __syncthreads();   // buf[p^1] staged & all buf[p] reads done
        p ^= 1;
    }
}

extern "C" void kernel_launch(void* const* d_in, const int* in_sizes, int n_in,
                              void* d_out, int out_size, void* d_ws, size_t ws_size,
                              hipStream_t stream) {
    const float* q = (const float*)d_in[0];
    const float* k = (const float*)d_in[1];
    const float* v = (const float*)d_in[2];
    float* o  = (float*)d_out;
    float* hf = o + (long)BB * SS * HH * DD;
    float* G  = (float*)d_ws;

    int NG = 8;
    while (NG > 1 && (size_t)BB * HH * NG * DD * DD * 4 > ws_size) NG >>= 1;
    int CPG = NTC / NG;
    float scale = 1.0f / sqrtf((float)DD);

    ksum_kernel<<<dim3(NG, HH, BB), 512, 0, stream>>>(k, v, G, CPG, NG);
    prefix_kernel<<<dim3(256, 1, 1), 256, 0, stream>>>(G, hf, NG);
    scan_kernel<<<dim3(NG, HH, BB), 512, 0, stream>>>(q, k, v, G, o, CPG, NG, scale);
}